// Round 1
// baseline (895.780 us; speedup 1.0000x reference)
//
#include <hip/hip_runtime.h>

// MSDNet fused pipeline on gfx950.
// Layout: d_ws holds 31 zero-halo-padded planes per batch:
//   subplane index (c*B + b), each HP x WP floats, interior at [HALO..HALO+511].
// Halo = 12 >= max dilation 10 -> depth kernels are branch-free.

#define MSD_DEPTH 30
#define NB 4
#define IH 512
#define IW 512
#define HALO 12
#define WP (IW + 2 * HALO) /* 536 */
#define HP (IH + 2 * HALO) /* 536 */
#define PLANE ((size_t)WP * (size_t)HP)         /* 287296 */
#define CSTRIDE ((size_t)NB * PLANE)            /* channel stride in floats */
#define NPIX (NB * IH * IW)                     /* 1048576 */

// ---------------------------------------------------------------------------
// Zero only the halo regions of all (DEPTH+1)*NB subplanes.
// Per subplane halo elems: WP*HP - IW*IH = 25152.
__global__ __launch_bounds__(256) void zero_halo_kernel(float* __restrict__ ws) {
    const int per = WP * HP - IW * IH; // 25152
    long idx = (long)blockIdx.x * 256 + threadIdx.x;
    const long total = (long)per * (MSD_DEPTH + 1) * NB;
    if (idx >= total) return;
    int sub = (int)(idx / per);
    int rem = (int)(idx % per);
    int r, c;
    if (rem < HALO * WP) {                    // top rows 0..HALO-1
        r = rem / WP;
        c = rem % WP;
    } else if (rem < 2 * HALO * WP) {         // bottom rows
        int t = rem - HALO * WP;
        r = (IH + HALO) + t / WP;
        c = t % WP;
    } else {                                  // left/right columns of interior rows
        int t = rem - 2 * HALO * WP;
        r = HALO + t / (2 * HALO);
        int u = t % (2 * HALO);
        c = (u < HALO) ? u : (IW + u);        // 0..11 or 524..535
    }
    ws[(size_t)sub * PLANE + (size_t)r * WP + c] = 0.0f;
}

// ---------------------------------------------------------------------------
// Plane 0 = x * sin_w + sin_b, written into padded interior.
__global__ __launch_bounds__(256) void scale_in_kernel(const float* __restrict__ x,
                                                       float* __restrict__ ws,
                                                       const float* __restrict__ sw,
                                                       const float* __restrict__ sb) {
    int idx = blockIdx.x * 256 + threadIdx.x; // 0..NPIX-1
    int w = idx & (IW - 1);
    int t = idx >> 9;
    int h = t & (IH - 1);
    int b = t >> 9;
    float v = x[idx] * sw[0] + sb[0];
    ws[(size_t)b * PLANE + (size_t)(h + HALO) * WP + (w + HALO)] = v;
}

// ---------------------------------------------------------------------------
// Depth kernel: h_I = relu(bias[I] + sum_c conv3x3_dilD(plane_c, Wmsd[I,c])).
// Writes plane I+1. For I==29 also fuses the 1x1 conv + output affine.
template <int I>
__global__ __launch_bounds__(256) void depth_kernel(float* __restrict__ ws,
                                                    const float* __restrict__ Wmsd,
                                                    const float* __restrict__ bias,
                                                    const float* __restrict__ convW,
                                                    const float* __restrict__ convB,
                                                    const float* __restrict__ soutw,
                                                    const float* __restrict__ soutb,
                                                    float* __restrict__ out) {
    constexpr int D = (I % 10) + 1;
    constexpr int NC = I + 1;
    constexpr bool LAST = (I == MSD_DEPTH - 1);

    int idx = blockIdx.x * 256 + threadIdx.x; // one pixel per thread
    int w = idx & (IW - 1);
    int t = idx >> 9;
    int h = t & (IH - 1);
    int b = t >> 9;

    const float* base = ws + (size_t)b * PLANE + (size_t)(h + HALO) * WP + (w + HALO);
    const float* wr = Wmsd + (size_t)I * (MSD_DEPTH * 9); // row I of (30,30,3,3)

    float acc = 0.0f;
    float ydot = 0.0f;
    for (int c = 0; c < NC; ++c) {
        const float* p = base + (size_t)c * CSTRIDE;
        const float* wk = wr + c * 9; // uniform -> scalar loads
        float ctr = p[0];
        acc += wk[0] * p[-D * WP - D] + wk[1] * p[-D * WP] + wk[2] * p[-D * WP + D]
             + wk[3] * p[-D]          + wk[4] * ctr        + wk[5] * p[D]
             + wk[6] * p[D * WP - D]  + wk[7] * p[D * WP]  + wk[8] * p[D * WP + D];
        if (LAST) ydot += convW[c] * ctr;
    }
    float hv = acc + bias[I];
    hv = hv > 0.0f ? hv : 0.0f;
    ws[(size_t)(NC * NB + b) * PLANE + (size_t)(h + HALO) * WP + (w + HALO)] = hv;

    if (LAST) {
        float y = ydot + convW[MSD_DEPTH] * hv + convB[0];
        y = y * soutw[0] + soutb[0];
        out[idx] = y;
    }
}

// ---------------------------------------------------------------------------
extern "C" void kernel_launch(void* const* d_in, const int* in_sizes, int n_in,
                              void* d_out, int out_size, void* d_ws, size_t ws_size,
                              hipStream_t stream) {
    const float* x     = (const float*)d_in[0];
    const float* Wmsd  = (const float*)d_in[1];
    const float* bias  = (const float*)d_in[2];
    const float* convW = (const float*)d_in[3];
    const float* convB = (const float*)d_in[4];
    const float* sinw  = (const float*)d_in[5];
    const float* sinb  = (const float*)d_in[6];
    const float* soutw = (const float*)d_in[7];
    const float* soutb = (const float*)d_in[8];
    float* out = (float*)d_out;
    float* ws  = (float*)d_ws;

    const long halo_total = (long)(WP * HP - IW * IH) * (MSD_DEPTH + 1) * NB;
    int zb = (int)((halo_total + 255) / 256);
    zero_halo_kernel<<<zb, 256, 0, stream>>>(ws);

    const int blocks = NPIX / 256; // 4096
    scale_in_kernel<<<blocks, 256, 0, stream>>>(x, ws, sinw, sinb);

#define LNCH(I) depth_kernel<I><<<blocks, 256, 0, stream>>>(ws, Wmsd, bias, convW, convB, soutw, soutb, out);
    LNCH(0)  LNCH(1)  LNCH(2)  LNCH(3)  LNCH(4)
    LNCH(5)  LNCH(6)  LNCH(7)  LNCH(8)  LNCH(9)
    LNCH(10) LNCH(11) LNCH(12) LNCH(13) LNCH(14)
    LNCH(15) LNCH(16) LNCH(17) LNCH(18) LNCH(19)
    LNCH(20) LNCH(21) LNCH(22) LNCH(23) LNCH(24)
    LNCH(25) LNCH(26) LNCH(27) LNCH(28) LNCH(29)
#undef LNCH
}